// Round 9
// baseline (1939.550 us; speedup 1.0000x reference)
//
#include <hip/hip_runtime.h>
#include <hip/hip_bf16.h>
#include <hip/hip_cooperative_groups.h>
#include <cstddef>

namespace cg = cooperative_groups;

#define B_ 16
#define T_ 64
#define N_ 1024
#define D_ 32
#define H_ 64
#define C_ 32
#define O_ 12

typedef __attribute__((ext_vector_type(8))) short bf16x8;
typedef __attribute__((ext_vector_type(4))) float f32x4;
#define MFMA16(a,b,c) __builtin_amdgcn_mfma_f32_16x16x32_bf16(a,b,c,0,0,0)

__device__ __forceinline__ float d_tanhf(float v){ float e = __expf(2.f*v); return 1.f - 2.f/(e + 1.f); }
__device__ __forceinline__ float d_sigmf(float v){ return 1.f/(1.f + __expf(-v)); }
__device__ __forceinline__ short f2bs(float f){
  __hip_bfloat16 h = __float2bfloat16(f);
  union { __hip_bfloat16 b; short s; } u; u.b = h; return u.s;
}
__device__ __forceinline__ unsigned int packbf(float lo, float hi){
  return (unsigned int)(unsigned short)f2bs(lo) | ((unsigned int)(unsigned short)f2bs(hi) << 16);
}

// ---------------- K1: Ubf[b,n,0:64]=bf16(m1), [64:128]=bf16(m2) ----------------
__global__ __launch_bounds__(128) void k_u(const float* __restrict__ x,
    const float* __restrict__ w1, const float* __restrict__ b1,
    const float* __restrict__ w2, const float* __restrict__ b2,
    unsigned short* __restrict__ Ubf)
{
  int row = blockIdx.x;
  int b = row & 15, n = row >> 4;
  int t = threadIdx.x;
  int hh = t & (H_-1), which = t >> 6;
  __shared__ float xl[D_];
  if (t < D_) xl[t] = x[(((size_t)b*T_ + (T_-1))*N_ + n)*D_ + t];
  __syncthreads();
  const float* w  = which ? w2 : w1;
  const float* bi = which ? b2 : b1;
  float acc = bi[hh];
  #pragma unroll
  for (int d = 0; d < D_; ++d) acc += xl[d] * w[d*H_ + hh];
  Ubf[((size_t)b*N_ + n)*128 + which*H_ + hh] = (unsigned short)f2bs(acc);
}

// ---------------- K2: adj = softmax(tanh(S)) via MFMA; also emits bf16 copy ----------------
__global__ __launch_bounds__(512, 1) void k_adj(const unsigned short* __restrict__ Ubf,
                                                float* __restrict__ adj,
                                                unsigned short* __restrict__ adjbf,
                                                int write_bf)
{
  __shared__ float rsum[2][64];
  int b  = blockIdx.x & 15;
  int n0 = (blockIdx.x >> 4) * 64;
  int tid = threadIdx.x;
  int w = tid >> 6, l = tid & 63;
  int wr = w & 3, wc = w >> 2;
  int l15 = l & 15, lg = l >> 4;
  const unsigned short* Ub = Ubf + (size_t)b*N_*128;

  bf16x8 afr[4];
  #pragma unroll
  for (int kc = 0; kc < 4; ++kc)
    afr[kc] = *reinterpret_cast<const bf16x8*>(Ub + (size_t)(n0 + 16*wr + l15)*128 + 32*kc + 8*lg);

  f32x4 acc[32];
  #pragma unroll
  for (int ct = 0; ct < 32; ++ct) acc[ct] = (f32x4){0.f,0.f,0.f,0.f};

  #pragma unroll
  for (int ct = 0; ct < 32; ++ct) {
    const unsigned short* Um = Ub + (size_t)(512*wc + 16*ct + l15)*128;
    #pragma unroll
    for (int kc = 0; kc < 4; ++kc) {
      int ks = (32*kc + 8*lg + 64) & 127;
      bf16x8 bfr = *reinterpret_cast<const bf16x8*>(Um + ks);
      acc[ct] = MFMA16(afr[kc], bfr, acc[ct]);
    }
  }

  float rs[4] = {0.f,0.f,0.f,0.f};
  #pragma unroll
  for (int ct = 0; ct < 32; ++ct) {
    #pragma unroll
    for (int r = 0; r < 4; ++r) {
      float e = __expf(d_tanhf(acc[ct][r]));
      acc[ct][r] = e;
      rs[r] += e;
    }
  }
  #pragma unroll
  for (int r = 0; r < 4; ++r) {
    float s = rs[r];
    s += __shfl_xor(s, 1); s += __shfl_xor(s, 2);
    s += __shfl_xor(s, 4); s += __shfl_xor(s, 8);
    rs[r] = s;
  }
  if (l15 == 0) {
    #pragma unroll
    for (int r = 0; r < 4; ++r)
      rsum[wc][16*wr + 4*lg + r] = rs[r];
  }
  __syncthreads();
  float inv[4];
  #pragma unroll
  for (int r = 0; r < 4; ++r) {
    int row = 16*wr + 4*lg + r;
    inv[r] = 1.0f / (rsum[0][row] + rsum[1][row]);
  }
  #pragma unroll
  for (int ct = 0; ct < 32; ++ct) {
    #pragma unroll
    for (int r = 0; r < 4; ++r) {
      int n = n0 + 16*wr + 4*lg + r;
      int m = 512*wc + 16*ct + l15;
      float v = acc[ct][r] * inv[r];
      size_t idx = ((size_t)b*N_ + n)*N_ + m;
      __builtin_nontemporal_store(v, &adj[idx]);
      if (write_bf) adjbf[idx] = (unsigned short)f2bs(v);
    }
  }
}

// ---------------- K3: gated dilated convs, last position -> h (+ bf16 zbT) ----------------
__global__ __launch_bounds__(256) void k_conv(const float* __restrict__ x,
    const float* __restrict__ fw1,const float* __restrict__ fb1,const float* __restrict__ gw1,const float* __restrict__ gb1,
    const float* __restrict__ fw2,const float* __restrict__ fb2,const float* __restrict__ gw2,const float* __restrict__ gb2,
    const float* __restrict__ fw3,const float* __restrict__ fb3,const float* __restrict__ gw3,const float* __restrict__ gb3,
    float* __restrict__ h, unsigned short* __restrict__ zbT)
{
  __shared__ float xs[16][15][32];
  __shared__ float y1[16][7][32];
  __shared__ float y2[16][3][32];
  __shared__ float4 wl4[1600];
  int tid = threadIdx.x;
  int b  = blockIdx.x & 15;
  int n0 = (blockIdx.x >> 4) * 16;

  for (int l = tid; l < 1920; l += 256) {
    int t = l >> 7, r = l & 127;
    int nl = r >> 3, d4 = r & 7;
    float4 v = reinterpret_cast<const float4*>(x)[(((size_t)b*T_ + 49 + t)*N_ + n0 + nl)*8 + d4];
    *reinterpret_cast<float4*>(&xs[nl][t][d4*4]) = v;
  }
  for (int l = tid; l < 768; l += 256) {
    int cc = l / 24, f4 = l - cc*24;
    wl4[cc*25 + f4]       = reinterpret_cast<const float4*>(fw1)[l];
    wl4[800 + cc*25 + f4] = reinterpret_cast<const float4*>(gw1)[l];
  }
  __syncthreads();

  int sg = tid >> 5, c = tid & 31;

  float af[2][7], ag[2][7];
  {
    float bf = fb1[c], bg = gb1[c];
    #pragma unroll
    for (int ss=0; ss<2; ++ss)
      #pragma unroll
      for (int p=0;p<7;++p){ af[ss][p]=bf; ag[ss][p]=bg; }
  }
  for (int ic4 = 0; ic4 < 8; ++ic4) {
    float wfl[12], wgl[12];
    {
      const float4* fp = wl4 + c*25 + ic4*3;
      const float4* gp = wl4 + 800 + c*25 + ic4*3;
      #pragma unroll
      for (int q=0;q<3;++q){
        float4 a = fp[q], g = gp[q];
        wfl[q*4+0]=a.x; wfl[q*4+1]=a.y; wfl[q*4+2]=a.z; wfl[q*4+3]=a.w;
        wgl[q*4+0]=g.x; wgl[q*4+1]=g.y; wgl[q*4+2]=g.z; wgl[q*4+3]=g.w;
      }
    }
    #pragma unroll
    for (int ss=0; ss<2; ++ss) {
      int s = sg*2 + ss;
      #pragma unroll
      for (int p = 0; p < 7; ++p) {
        float4 xa = *reinterpret_cast<const float4*>(&xs[s][2*p+0][ic4*4]);
        float4 xb = *reinterpret_cast<const float4*>(&xs[s][2*p+1][ic4*4]);
        float4 xc = *reinterpret_cast<const float4*>(&xs[s][2*p+2][ic4*4]);
        af[ss][p] += xa.x*wfl[0] + xb.x*wfl[1] + xc.x*wfl[2]
                   + xa.y*wfl[3] + xb.y*wfl[4] + xc.y*wfl[5]
                   + xa.z*wfl[6] + xb.z*wfl[7] + xc.z*wfl[8]
                   + xa.w*wfl[9] + xb.w*wfl[10]+ xc.w*wfl[11];
        ag[ss][p] += xa.x*wgl[0] + xb.x*wgl[1] + xc.x*wgl[2]
                   + xa.y*wgl[3] + xb.y*wgl[4] + xc.y*wgl[5]
                   + xa.z*wgl[6] + xb.z*wgl[7] + xc.z*wgl[8]
                   + xa.w*wgl[9] + xb.w*wgl[10]+ xc.w*wgl[11];
      }
    }
  }
  #pragma unroll
  for (int ss=0; ss<2; ++ss)
    #pragma unroll
    for (int p=0;p<7;++p) y1[sg*2+ss][p][c] = d_tanhf(af[ss][p]) * d_sigmf(ag[ss][p]);
  __syncthreads();

  for (int l = tid; l < 768; l += 256) {
    int cc = l / 24, f4 = l - cc*24;
    wl4[cc*25 + f4]       = reinterpret_cast<const float4*>(fw2)[l];
    wl4[800 + cc*25 + f4] = reinterpret_cast<const float4*>(gw2)[l];
  }
  __syncthreads();

  float af2[2][3], ag2[2][3];
  {
    float bf = fb2[c], bg = gb2[c];
    #pragma unroll
    for (int ss=0; ss<2; ++ss)
      #pragma unroll
      for (int r=0;r<3;++r){ af2[ss][r]=bf; ag2[ss][r]=bg; }
  }
  for (int ic4 = 0; ic4 < 8; ++ic4) {
    float wfl[12], wgl[12];
    {
      const float4* fp = wl4 + c*25 + ic4*3;
      const float4* gp = wl4 + 800 + c*25 + ic4*3;
      #pragma unroll
      for (int q=0;q<3;++q){
        float4 a = fp[q], g = gp[q];
        wfl[q*4+0]=a.x; wfl[q*4+1]=a.y; wfl[q*4+2]=a.z; wfl[q*4+3]=a.w;
        wgl[q*4+0]=g.x; wgl[q*4+1]=g.y; wgl[q*4+2]=g.z; wgl[q*4+3]=g.w;
      }
    }
    #pragma unroll
    for (int ss=0; ss<2; ++ss) {
      int s = sg*2 + ss;
      #pragma unroll
      for (int r = 0; r < 3; ++r) {
        float4 xa = *reinterpret_cast<const float4*>(&y1[s][2*r+0][ic4*4]);
        float4 xb = *reinterpret_cast<const float4*>(&y1[s][2*r+1][ic4*4]);
        float4 xc = *reinterpret_cast<const float4*>(&y1[s][2*r+2][ic4*4]);
        af2[ss][r] += xa.x*wfl[0] + xb.x*wfl[1] + xc.x*wfl[2]
                    + xa.y*wfl[3] + xb.y*wfl[4] + xc.y*wfl[5]
                    + xa.z*wfl[6] + xb.z*wfl[7] + xc.z*wfl[8]
                    + xa.w*wfl[9] + xb.w*wfl[10]+ xc.w*wfl[11];
        ag2[ss][r] += xa.x*wgl[0] + xb.x*wgl[1] + xc.x*wgl[2]
                    + xa.y*wgl[3] + xb.y*wgl[4] + xc.y*wgl[5]
                    + xa.z*wgl[6] + xb.z*wgl[7] + xc.z*wgl[8]
                    + xa.w*wgl[9] + xb.w*wgl[10]+ xc.w*wgl[11];
      }
    }
  }
  #pragma unroll
  for (int ss=0; ss<2; ++ss)
    #pragma unroll
    for (int r=0;r<3;++r) y2[sg*2+ss][r][c] = d_tanhf(af2[ss][r]) * d_sigmf(ag2[ss][r]);
  __syncthreads();

  for (int l = tid; l < 768; l += 256) {
    int cc = l / 24, f4 = l - cc*24;
    wl4[cc*25 + f4]       = reinterpret_cast<const float4*>(fw3)[l];
    wl4[800 + cc*25 + f4] = reinterpret_cast<const float4*>(gw3)[l];
  }
  __syncthreads();

  float af3[2], ag3[2];
  {
    float bf = fb3[c], bg = gb3[c];
    af3[0]=bf; af3[1]=bf; ag3[0]=bg; ag3[1]=bg;
  }
  for (int ic4 = 0; ic4 < 8; ++ic4) {
    float wfl[12], wgl[12];
    {
      const float4* fp = wl4 + c*25 + ic4*3;
      const float4* gp = wl4 + 800 + c*25 + ic4*3;
      #pragma unroll
      for (int q=0;q<3;++q){
        float4 a = fp[q], g = gp[q];
        wfl[q*4+0]=a.x; wfl[q*4+1]=a.y; wfl[q*4+2]=a.z; wfl[q*4+3]=a.w;
        wgl[q*4+0]=g.x; wgl[q*4+1]=g.y; wgl[q*4+2]=g.z; wgl[q*4+3]=g.w;
      }
    }
    #pragma unroll
    for (int ss=0; ss<2; ++ss) {
      int s = sg*2 + ss;
      float4 xa = *reinterpret_cast<const float4*>(&y2[s][0][ic4*4]);
      float4 xb = *reinterpret_cast<const float4*>(&y2[s][1][ic4*4]);
      float4 xc = *reinterpret_cast<const float4*>(&y2[s][2][ic4*4]);
      af3[ss] += xa.x*wfl[0] + xb.x*wfl[1] + xc.x*wfl[2]
               + xa.y*wfl[3] + xb.y*wfl[4] + xc.y*wfl[5]
               + xa.z*wfl[6] + xb.z*wfl[7] + xc.z*wfl[8]
               + xa.w*wfl[9] + xb.w*wfl[10]+ xc.w*wfl[11];
      ag3[ss] += xa.x*wgl[0] + xb.x*wgl[1] + xc.x*wgl[2]
               + xa.y*wgl[3] + xb.y*wgl[4] + xc.y*wgl[5]
               + xa.z*wgl[6] + xb.z*wgl[7] + xc.z*wgl[8]
               + xa.w*wgl[9] + xb.w*wgl[10]+ xc.w*wgl[11];
    }
  }
  #pragma unroll
  for (int ss=0; ss<2; ++ss) {
    float hv = d_tanhf(af3[ss]) * d_sigmf(ag3[ss]);
    int n = n0 + sg*2 + ss;
    h[((size_t)b*N_ + n)*C_ + c] = hv;
    zbT[((size_t)b*32 + c)*N_ + n] = (unsigned short)f2bs(hv);
  }
}

// ---------------- K4 (cooperative): full 10-iteration propagation + output GEMM ----------------
// grid = 1024 blocks (16 b x 64 g), 256 thr = 4 waves (wc x wk). Block owns 16 rows forever.
// A-slice in registers (16 bf16x8); z,h own-rows in f32 registers; zbT global for mixing.
__global__ __launch_bounds__(256, 4) void k_prop_loop(const unsigned short* __restrict__ adjbf,
    const unsigned short* __restrict__ zb0, unsigned short* __restrict__ zb1,
    const float* __restrict__ h, const float* __restrict__ wo,
    const float* __restrict__ bo, float* __restrict__ out)
{
  __shared__ float red[2][16][17];
  __shared__ float zfin[16][33];
  cg::grid_group grid = cg::this_grid();

  int b = blockIdx.x & 15;
  int g = blockIdx.x >> 4;
  int tid = threadIdx.x;
  int w = tid >> 6, l = tid & 63;
  int wk = w >> 1, wc = w & 1;
  int l15 = l & 15, lg = l >> 4;
  int n_base = g*16;
  int c = 16*wc + l15;

  // A-slice into registers: rows n_base+l15, K-half wk*512
  const unsigned short* A = adjbf + ((size_t)b*N_ + n_base + l15)*N_ + wk*512;
  bf16x8 Areg[16];
  #pragma unroll
  for (int kc = 0; kc < 16; ++kc)
    Areg[kc] = *reinterpret_cast<const bf16x8*>(A + 32*kc + 8*lg);

  // own rows' h and z (wk==0 threads only): rows n_base+4*lg+r, col c
  float h_own[4], z_own[4];
  if (wk == 0) {
    #pragma unroll
    for (int r = 0; r < 4; ++r) {
      h_own[r] = h[((size_t)b*N_ + n_base + 4*lg + r)*32 + c];
      z_own[r] = h_own[r];
    }
  }

  const unsigned short* zi = zb0;
  unsigned short* zo = zb1;

  for (int it = 0; it < 10; ++it) {
    const unsigned short* Zb = zi + ((size_t)b*32 + c)*N_ + wk*512;
    f32x4 acc0 = {0.f,0.f,0.f,0.f}, acc1 = {0.f,0.f,0.f,0.f};
    #pragma unroll
    for (int kc = 0; kc < 16; kc += 2) {
      int k0 = 32*kc + 8*lg;
      bf16x8 zf0 = *reinterpret_cast<const bf16x8*>(Zb + k0);
      bf16x8 zf1 = *reinterpret_cast<const bf16x8*>(Zb + k0 + 32);
      acc0 = MFMA16(Areg[kc], zf0, acc0);
      acc1 = MFMA16(Areg[kc+1], zf1, acc1);
    }
    f32x4 acc = acc0 + acc1;

    if (wk == 1) {
      #pragma unroll
      for (int r = 0; r < 4; ++r) red[wc][4*lg + r][l15] = acc[r];
    }
    __syncthreads();
    if (wk == 0) {
      float v[4];
      #pragma unroll
      for (int r = 0; r < 4; ++r) {
        float a = acc[r] + red[wc][4*lg + r][l15];
        v[r] = 0.1f*h_own[r] + 0.45f*z_own[r] + 0.45f*a;
        z_own[r] = v[r];
      }
      // write own 4 consecutive n-slots of zbT[b][c][*] as bf16 (8B store)
      uint2 pv;
      pv.x = packbf(v[0], v[1]);
      pv.y = packbf(v[2], v[3]);
      *reinterpret_cast<uint2*>(zo + ((size_t)b*32 + c)*N_ + n_base + 4*lg) = pv;
    }
    if (it < 9) {
      __threadfence();
      grid.sync();
      const unsigned short* t = zi; zi = zo; zo = (unsigned short*)t;
    }
  }

  // epilogue: out = relu(z) @ wo + bo for own 16 rows
  if (wk == 0) {
    #pragma unroll
    for (int r = 0; r < 4; ++r)
      zfin[4*lg + r][c] = fmaxf(z_own[r], 0.f);
  }
  __syncthreads();
  if (tid < 192) {
    int n = tid / 12, o = tid - n*12;
    float acc = bo[o];
    #pragma unroll
    for (int cc = 0; cc < 32; ++cc) acc += zfin[n][cc] * wo[cc*O_ + o];
    out[((size_t)b*N_ + n_base + n)*O_ + o] = acc;
  }
}

// ---------------- Fallback K4: single-iteration propm (bf16 adj), 2-way K-split ----------------
__global__ __launch_bounds__(256) void k_propm_bf(const unsigned short* __restrict__ adjbf,
    const unsigned short* __restrict__ zbT, const float* __restrict__ h,
    const float* __restrict__ zin, float* __restrict__ zout,
    unsigned short* __restrict__ zbTout)
{
  __shared__ float red[2][16][17];
  int b = blockIdx.x & 15;
  int g = blockIdx.x >> 4;
  int tid = threadIdx.x;
  int w = tid >> 6, l = tid & 63;
  int wk = w >> 1, wc = w & 1;
  int l15 = l & 15, lg = l >> 4;
  int n_base = g*16;

  const unsigned short* A = adjbf + ((size_t)b*N_ + n_base + l15)*N_ + wk*512;
  const unsigned short* Z = zbT + ((size_t)b*32 + 16*wc + l15)*N_ + wk*512;

  f32x4 acc0 = {0.f,0.f,0.f,0.f}, acc1 = {0.f,0.f,0.f,0.f};
  #pragma unroll
  for (int kc = 0; kc < 16; kc += 2) {
    int k0 = 32*kc + 8*lg;
    bf16x8 a0 = *reinterpret_cast<const bf16x8*>(A + k0);
    bf16x8 z0 = *reinterpret_cast<const bf16x8*>(Z + k0);
    bf16x8 a1 = *reinterpret_cast<const bf16x8*>(A + k0 + 32);
    bf16x8 z1 = *reinterpret_cast<const bf16x8*>(Z + k0 + 32);
    acc0 = MFMA16(a0, z0, acc0);
    acc1 = MFMA16(a1, z1, acc1);
  }
  f32x4 acc = acc0 + acc1;

  if (wk == 1) {
    #pragma unroll
    for (int r = 0; r < 4; ++r) red[wc][4*lg + r][l15] = acc[r];
  }
  __syncthreads();
  if (wk == 0) {
    int c = 16*wc + l15;
    #pragma unroll
    for (int r = 0; r < 4; ++r) {
      float a = acc[r] + red[wc][4*lg + r][l15];
      int n = n_base + 4*lg + r;
      size_t idx = ((size_t)b*N_ + n)*32 + c;
      float v = 0.1f*h[idx] + 0.45f*zin[idx] + 0.45f*a;
      zout[idx] = v;
      zbTout[((size_t)b*32 + c)*N_ + n] = (unsigned short)f2bs(v);
    }
  }
}

// ---------------- Fallback K5: out = relu(z) @ wo + bo ----------------
__global__ __launch_bounds__(256) void k_out(const float* __restrict__ z, const float* __restrict__ wo,
                                             const float* __restrict__ bo, float* __restrict__ out)
{
  int gid = blockIdx.x*256 + threadIdx.x;
  if (gid >= B_*N_*O_) return;
  int o = gid % O_; int row = gid / O_;
  const float* zr = z + (size_t)row*C_;
  float acc = bo[o];
  #pragma unroll
  for (int cc = 0; cc < C_; ++cc) acc += fmaxf(zr[cc], 0.f) * wo[cc*O_ + o];
  out[gid] = acc;
}

extern "C" void kernel_launch(void* const* d_in, const int* in_sizes, int n_in,
                              void* d_out, int out_size, void* d_ws, size_t ws_size,
                              hipStream_t stream)
{
  const float* x   = (const float*)d_in[0];
  const float* w1  = (const float*)d_in[1];
  const float* b1  = (const float*)d_in[2];
  const float* w2  = (const float*)d_in[3];
  const float* b2  = (const float*)d_in[4];
  const float* fw1 = (const float*)d_in[5];  const float* fb1 = (const float*)d_in[6];
  const float* gw1 = (const float*)d_in[7];  const float* gb1 = (const float*)d_in[8];
  const float* fw2 = (const float*)d_in[9];  const float* fb2 = (const float*)d_in[10];
  const float* gw2 = (const float*)d_in[11]; const float* gb2 = (const float*)d_in[12];
  const float* fw3 = (const float*)d_in[13]; const float* fb3 = (const float*)d_in[14];
  const float* gw3 = (const float*)d_in[15]; const float* gb3 = (const float*)d_in[16];
  const float* wo  = (const float*)d_in[17]; const float* bo  = (const float*)d_in[18];

  float* out = (float*)d_out;
  float* adj = out + (size_t)B_*N_*O_;

  char* ws = (char*)d_ws;
  unsigned short* Ubf  = (unsigned short*)ws;                       // 4 MB
  float* h             = (float*)(ws + (4ull<<20));                 // 2 MB
  float* z0            = (float*)(ws + (6ull<<20));                 // 2 MB (fallback)
  float* z1            = (float*)(ws + (8ull<<20));                 // 2 MB (fallback)
  unsigned short* zbT0 = (unsigned short*)(ws + (10ull<<20));       // 1 MB
  unsigned short* zbT1 = (unsigned short*)(ws + (11ull<<20));       // 1 MB
  unsigned short* adjbf= (unsigned short*)(ws + (12ull<<20));       // 32 MB
  bool use_bf = ws_size >= (44ull<<20);

  k_u<<<B_*N_, 128, 0, stream>>>(x, w1, b1, w2, b2, Ubf);
  k_adj<<<B_*16, 512, 0, stream>>>(Ubf, adj, adjbf, use_bf ? 1 : 0);
  k_conv<<<B_*N_/16, 256, 0, stream>>>(x, fw1,fb1,gw1,gb1, fw2,fb2,gw2,gb2, fw3,fb3,gw3,gb3, h, zbT0);

  bool done = false;
  if (use_bf) {
    void* kargs[] = { (void*)&adjbf, (void*)&zbT0, (void*)&zbT1, (void*)&h,
                      (void*)&wo, (void*)&bo, (void*)&out };
    hipError_t err = hipLaunchCooperativeKernel((const void*)k_prop_loop,
                        dim3(B_*64), dim3(256), kargs, 0, stream);
    if (err == hipSuccess) done = true;
    else (void)hipGetLastError();   // clear sticky error, fall through
  }

  if (!done) {
    // fallback: 10 separate dispatches + k_out (requires use_bf workspace; if even
    // that is absent we still run it against adjbf==garbage-free path: use_bf implies
    // adjbf written; for !use_bf run propm on fp32 adj is not available here, so
    // convert via k_adj write_bf=1 only when workspace allows. ws_size has always
    // been >= 44MB in this harness.)
    const float* zi = h;
    const unsigned short* zbi = zbT0;
    float* zfbuf[2] = {z0, z1};
    unsigned short* zbbuf[2] = {zbT1, zbT0};
    for (int it = 0; it < 10; ++it) {
      float* zo = zfbuf[it & 1];
      unsigned short* zbo = zbbuf[it & 1];
      k_propm_bf<<<B_*64, 256, 0, stream>>>(adjbf, zbi, h, zi, zo, zbo);
      zi = zo; zbi = zbo;
    }
    k_out<<<(B_*N_*O_ + 255)/256, 256, 0, stream>>>(zi, wo, bo, out);
  }
}

// Round 10
// 297.003 us; speedup vs baseline: 6.5304x; 6.5304x over previous
//
#include <hip/hip_runtime.h>
#include <hip/hip_bf16.h>
#include <cstddef>

#define B_ 16
#define T_ 64
#define N_ 1024
#define D_ 32
#define H_ 64
#define C_ 32
#define O_ 12

typedef __attribute__((ext_vector_type(8))) short bf16x8;
typedef __attribute__((ext_vector_type(4))) float f32x4;
#define MFMA16(a,b,c) __builtin_amdgcn_mfma_f32_16x16x32_bf16(a,b,c,0,0,0)

__device__ __forceinline__ float d_tanhf(float v){ float e = __expf(2.f*v); return 1.f - 2.f/(e + 1.f); }
__device__ __forceinline__ float d_sigmf(float v){ return 1.f/(1.f + __expf(-v)); }
__device__ __forceinline__ short f2bs(float f){
  __hip_bfloat16 h = __float2bfloat16(f);
  union { __hip_bfloat16 b; short s; } u; u.b = h; return u.s;
}
__device__ __forceinline__ unsigned int packbf(float lo, float hi){
  return (unsigned int)(unsigned short)f2bs(lo) | ((unsigned int)(unsigned short)f2bs(hi) << 16);
}

// ---------------- K1: Ubf[b,n,0:64]=bf16(m1), [64:128]=bf16(m2) ----------------
__global__ __launch_bounds__(128) void k_u(const float* __restrict__ x,
    const float* __restrict__ w1, const float* __restrict__ b1,
    const float* __restrict__ w2, const float* __restrict__ b2,
    unsigned short* __restrict__ Ubf)
{
  int row = blockIdx.x;
  int b = row & 15, n = row >> 4;
  int t = threadIdx.x;
  int hh = t & (H_-1), which = t >> 6;
  __shared__ float xl[D_];
  if (t < D_) xl[t] = x[(((size_t)b*T_ + (T_-1))*N_ + n)*D_ + t];
  __syncthreads();
  const float* w  = which ? w2 : w1;
  const float* bi = which ? b2 : b1;
  float acc = bi[hh];
  #pragma unroll
  for (int d = 0; d < D_; ++d) acc += xl[d] * w[d*H_ + hh];
  Ubf[((size_t)b*N_ + n)*128 + which*H_ + hh] = (unsigned short)f2bs(acc);
}

// ---------------- K2: adj = softmax(tanh(S)) via MFMA; also emits bf16 copy ----------------
__global__ __launch_bounds__(512, 1) void k_adj(const unsigned short* __restrict__ Ubf,
                                                float* __restrict__ adj,
                                                unsigned short* __restrict__ adjbf,
                                                int write_bf)
{
  __shared__ float rsum[2][64];
  int b  = blockIdx.x & 15;
  int n0 = (blockIdx.x >> 4) * 64;
  int tid = threadIdx.x;
  int w = tid >> 6, l = tid & 63;
  int wr = w & 3, wc = w >> 2;
  int l15 = l & 15, lg = l >> 4;
  const unsigned short* Ub = Ubf + (size_t)b*N_*128;

  bf16x8 afr[4];
  #pragma unroll
  for (int kc = 0; kc < 4; ++kc)
    afr[kc] = *reinterpret_cast<const bf16x8*>(Ub + (size_t)(n0 + 16*wr + l15)*128 + 32*kc + 8*lg);

  f32x4 acc[32];
  #pragma unroll
  for (int ct = 0; ct < 32; ++ct) acc[ct] = (f32x4){0.f,0.f,0.f,0.f};

  #pragma unroll
  for (int ct = 0; ct < 32; ++ct) {
    const unsigned short* Um = Ub + (size_t)(512*wc + 16*ct + l15)*128;
    #pragma unroll
    for (int kc = 0; kc < 4; ++kc) {
      int ks = (32*kc + 8*lg + 64) & 127;
      bf16x8 bfr = *reinterpret_cast<const bf16x8*>(Um + ks);
      acc[ct] = MFMA16(afr[kc], bfr, acc[ct]);
    }
  }

  float rs[4] = {0.f,0.f,0.f,0.f};
  #pragma unroll
  for (int ct = 0; ct < 32; ++ct) {
    #pragma unroll
    for (int r = 0; r < 4; ++r) {
      float e = __expf(d_tanhf(acc[ct][r]));
      acc[ct][r] = e;
      rs[r] += e;
    }
  }
  #pragma unroll
  for (int r = 0; r < 4; ++r) {
    float s = rs[r];
    s += __shfl_xor(s, 1); s += __shfl_xor(s, 2);
    s += __shfl_xor(s, 4); s += __shfl_xor(s, 8);
    rs[r] = s;
  }
  if (l15 == 0) {
    #pragma unroll
    for (int r = 0; r < 4; ++r)
      rsum[wc][16*wr + 4*lg + r] = rs[r];
  }
  __syncthreads();
  float inv[4];
  #pragma unroll
  for (int r = 0; r < 4; ++r) {
    int row = 16*wr + 4*lg + r;
    inv[r] = 1.0f / (rsum[0][row] + rsum[1][row]);
  }
  #pragma unroll
  for (int ct = 0; ct < 32; ++ct) {
    #pragma unroll
    for (int r = 0; r < 4; ++r) {
      int n = n0 + 16*wr + 4*lg + r;
      int m = 512*wc + 16*ct + l15;
      float v = acc[ct][r] * inv[r];
      size_t idx = ((size_t)b*N_ + n)*N_ + m;
      __builtin_nontemporal_store(v, &adj[idx]);
      if (write_bf) adjbf[idx] = (unsigned short)f2bs(v);
    }
  }
}

// ---------------- K3: gated dilated convs, last position -> h (+ bf16 zbT) ----------------
__global__ __launch_bounds__(256) void k_conv(const float* __restrict__ x,
    const float* __restrict__ fw1,const float* __restrict__ fb1,const float* __restrict__ gw1,const float* __restrict__ gb1,
    const float* __restrict__ fw2,const float* __restrict__ fb2,const float* __restrict__ gw2,const float* __restrict__ gb2,
    const float* __restrict__ fw3,const float* __restrict__ fb3,const float* __restrict__ gw3,const float* __restrict__ gb3,
    float* __restrict__ h, unsigned short* __restrict__ zbT)
{
  __shared__ float xs[16][15][32];
  __shared__ float y1[16][7][32];
  __shared__ float y2[16][3][32];
  __shared__ float4 wl4[1600];
  int tid = threadIdx.x;
  int b  = blockIdx.x & 15;
  int n0 = (blockIdx.x >> 4) * 16;

  for (int l = tid; l < 1920; l += 256) {
    int t = l >> 7, r = l & 127;
    int nl = r >> 3, d4 = r & 7;
    float4 v = reinterpret_cast<const float4*>(x)[(((size_t)b*T_ + 49 + t)*N_ + n0 + nl)*8 + d4];
    *reinterpret_cast<float4*>(&xs[nl][t][d4*4]) = v;
  }
  for (int l = tid; l < 768; l += 256) {
    int cc = l / 24, f4 = l - cc*24;
    wl4[cc*25 + f4]       = reinterpret_cast<const float4*>(fw1)[l];
    wl4[800 + cc*25 + f4] = reinterpret_cast<const float4*>(gw1)[l];
  }
  __syncthreads();

  int sg = tid >> 5, c = tid & 31;

  float af[2][7], ag[2][7];
  {
    float bf = fb1[c], bg = gb1[c];
    #pragma unroll
    for (int ss=0; ss<2; ++ss)
      #pragma unroll
      for (int p=0;p<7;++p){ af[ss][p]=bf; ag[ss][p]=bg; }
  }
  for (int ic4 = 0; ic4 < 8; ++ic4) {
    float wfl[12], wgl[12];
    {
      const float4* fp = wl4 + c*25 + ic4*3;
      const float4* gp = wl4 + 800 + c*25 + ic4*3;
      #pragma unroll
      for (int q=0;q<3;++q){
        float4 a = fp[q], g = gp[q];
        wfl[q*4+0]=a.x; wfl[q*4+1]=a.y; wfl[q*4+2]=a.z; wfl[q*4+3]=a.w;
        wgl[q*4+0]=g.x; wgl[q*4+1]=g.y; wgl[q*4+2]=g.z; wgl[q*4+3]=g.w;
      }
    }
    #pragma unroll
    for (int ss=0; ss<2; ++ss) {
      int s = sg*2 + ss;
      #pragma unroll
      for (int p = 0; p < 7; ++p) {
        float4 xa = *reinterpret_cast<const float4*>(&xs[s][2*p+0][ic4*4]);
        float4 xb = *reinterpret_cast<const float4*>(&xs[s][2*p+1][ic4*4]);
        float4 xc = *reinterpret_cast<const float4*>(&xs[s][2*p+2][ic4*4]);
        af[ss][p] += xa.x*wfl[0] + xb.x*wfl[1] + xc.x*wfl[2]
                   + xa.y*wfl[3] + xb.y*wfl[4] + xc.y*wfl[5]
                   + xa.z*wfl[6] + xb.z*wfl[7] + xc.z*wfl[8]
                   + xa.w*wfl[9] + xb.w*wfl[10]+ xc.w*wfl[11];
        ag[ss][p] += xa.x*wgl[0] + xb.x*wgl[1] + xc.x*wgl[2]
                   + xa.y*wgl[3] + xb.y*wgl[4] + xc.y*wgl[5]
                   + xa.z*wgl[6] + xb.z*wgl[7] + xc.z*wgl[8]
                   + xa.w*wgl[9] + xb.w*wgl[10]+ xc.w*wgl[11];
      }
    }
  }
  #pragma unroll
  for (int ss=0; ss<2; ++ss)
    #pragma unroll
    for (int p=0;p<7;++p) y1[sg*2+ss][p][c] = d_tanhf(af[ss][p]) * d_sigmf(ag[ss][p]);
  __syncthreads();

  for (int l = tid; l < 768; l += 256) {
    int cc = l / 24, f4 = l - cc*24;
    wl4[cc*25 + f4]       = reinterpret_cast<const float4*>(fw2)[l];
    wl4[800 + cc*25 + f4] = reinterpret_cast<const float4*>(gw2)[l];
  }
  __syncthreads();

  float af2[2][3], ag2[2][3];
  {
    float bf = fb2[c], bg = gb2[c];
    #pragma unroll
    for (int ss=0; ss<2; ++ss)
      #pragma unroll
      for (int r=0;r<3;++r){ af2[ss][r]=bf; ag2[ss][r]=bg; }
  }
  for (int ic4 = 0; ic4 < 8; ++ic4) {
    float wfl[12], wgl[12];
    {
      const float4* fp = wl4 + c*25 + ic4*3;
      const float4* gp = wl4 + 800 + c*25 + ic4*3;
      #pragma unroll
      for (int q=0;q<3;++q){
        float4 a = fp[q], g = gp[q];
        wfl[q*4+0]=a.x; wfl[q*4+1]=a.y; wfl[q*4+2]=a.z; wfl[q*4+3]=a.w;
        wgl[q*4+0]=g.x; wgl[q*4+1]=g.y; wgl[q*4+2]=g.z; wgl[q*4+3]=g.w;
      }
    }
    #pragma unroll
    for (int ss=0; ss<2; ++ss) {
      int s = sg*2 + ss;
      #pragma unroll
      for (int r = 0; r < 3; ++r) {
        float4 xa = *reinterpret_cast<const float4*>(&y1[s][2*r+0][ic4*4]);
        float4 xb = *reinterpret_cast<const float4*>(&y1[s][2*r+1][ic4*4]);
        float4 xc = *reinterpret_cast<const float4*>(&y1[s][2*r+2][ic4*4]);
        af2[ss][r] += xa.x*wfl[0] + xb.x*wfl[1] + xc.x*wfl[2]
                    + xa.y*wfl[3] + xb.y*wfl[4] + xc.y*wfl[5]
                    + xa.z*wfl[6] + xb.z*wfl[7] + xc.z*wfl[8]
                    + xa.w*wfl[9] + xb.w*wfl[10]+ xc.w*wfl[11];
        ag2[ss][r] += xa.x*wgl[0] + xb.x*wgl[1] + xc.x*wgl[2]
                    + xa.y*wgl[3] + xb.y*wgl[4] + xc.y*wgl[5]
                    + xa.z*wgl[6] + xb.z*wgl[7] + xc.z*wgl[8]
                    + xa.w*wgl[9] + xb.w*wgl[10]+ xc.w*wgl[11];
      }
    }
  }
  #pragma unroll
  for (int ss=0; ss<2; ++ss)
    #pragma unroll
    for (int r=0;r<3;++r) y2[sg*2+ss][r][c] = d_tanhf(af2[ss][r]) * d_sigmf(ag2[ss][r]);
  __syncthreads();

  for (int l = tid; l < 768; l += 256) {
    int cc = l / 24, f4 = l - cc*24;
    wl4[cc*25 + f4]       = reinterpret_cast<const float4*>(fw3)[l];
    wl4[800 + cc*25 + f4] = reinterpret_cast<const float4*>(gw3)[l];
  }
  __syncthreads();

  float af3[2], ag3[2];
  {
    float bf = fb3[c], bg = gb3[c];
    af3[0]=bf; af3[1]=bf; ag3[0]=bg; ag3[1]=bg;
  }
  for (int ic4 = 0; ic4 < 8; ++ic4) {
    float wfl[12], wgl[12];
    {
      const float4* fp = wl4 + c*25 + ic4*3;
      const float4* gp = wl4 + 800 + c*25 + ic4*3;
      #pragma unroll
      for (int q=0;q<3;++q){
        float4 a = fp[q], g = gp[q];
        wfl[q*4+0]=a.x; wfl[q*4+1]=a.y; wfl[q*4+2]=a.z; wfl[q*4+3]=a.w;
        wgl[q*4+0]=g.x; wgl[q*4+1]=g.y; wgl[q*4+2]=g.z; wgl[q*4+3]=g.w;
      }
    }
    #pragma unroll
    for (int ss=0; ss<2; ++ss) {
      int s = sg*2 + ss;
      float4 xa = *reinterpret_cast<const float4*>(&y2[s][0][ic4*4]);
      float4 xb = *reinterpret_cast<const float4*>(&y2[s][1][ic4*4]);
      float4 xc = *reinterpret_cast<const float4*>(&y2[s][2][ic4*4]);
      af3[ss] += xa.x*wfl[0] + xb.x*wfl[1] + xc.x*wfl[2]
               + xa.y*wfl[3] + xb.y*wfl[4] + xc.y*wfl[5]
               + xa.z*wfl[6] + xb.z*wfl[7] + xc.z*wfl[8]
               + xa.w*wfl[9] + xb.w*wfl[10]+ xc.w*wfl[11];
      ag3[ss] += xa.x*wgl[0] + xb.x*wgl[1] + xc.x*wgl[2]
               + xa.y*wgl[3] + xb.y*wgl[4] + xc.y*wgl[5]
               + xa.z*wgl[6] + xb.z*wgl[7] + xc.z*wgl[8]
               + xa.w*wgl[9] + xb.w*wgl[10]+ xc.w*wgl[11];
    }
  }
  #pragma unroll
  for (int ss=0; ss<2; ++ss) {
    float hv = d_tanhf(af3[ss]) * d_sigmf(ag3[ss]);
    int n = n0 + sg*2 + ss;
    h[((size_t)b*N_ + n)*C_ + c] = hv;
    zbT[((size_t)b*32 + c)*N_ + n] = (unsigned short)f2bs(hv);
  }
}

// ---------------- K4: z' = 0.1h + 0.45z + 0.45 adj@z, 512 thr / 8 waves / K 4-way ----------------
// Grid 1024 (16 b x 64 g) x 8 waves, VGPR<=64 => 32 waves/CU. wk=K quarter, wc=c half.
__global__ __launch_bounds__(512) void k_propm_bf(const unsigned short* __restrict__ adjbf,
    const unsigned short* __restrict__ zbT, const float* __restrict__ h,
    const float* __restrict__ zin, float* __restrict__ zout,
    unsigned short* __restrict__ zbTout)
{
  __shared__ float red[3][2][16][17];
  int b = blockIdx.x & 15;
  int g = blockIdx.x >> 4;
  int tid = threadIdx.x;
  int w = tid >> 6, l = tid & 63;
  int wk = w >> 1, wc = w & 1;
  int l15 = l & 15, lg = l >> 4;
  int n_base = g*16;

  const unsigned short* A = adjbf + ((size_t)b*N_ + n_base + l15)*N_ + wk*256;
  const unsigned short* Z = zbT + ((size_t)b*32 + 16*wc + l15)*N_ + wk*256;

  f32x4 acc0 = {0.f,0.f,0.f,0.f}, acc1 = {0.f,0.f,0.f,0.f};
  #pragma unroll
  for (int kc = 0; kc < 8; kc += 2) {
    int k0 = 32*kc + 8*lg;
    bf16x8 a0 = *reinterpret_cast<const bf16x8*>(A + k0);
    bf16x8 z0 = *reinterpret_cast<const bf16x8*>(Z + k0);
    bf16x8 a1 = *reinterpret_cast<const bf16x8*>(A + k0 + 32);
    bf16x8 z1 = *reinterpret_cast<const bf16x8*>(Z + k0 + 32);
    acc0 = MFMA16(a0, z0, acc0);
    acc1 = MFMA16(a1, z1, acc1);
  }
  f32x4 acc = acc0 + acc1;

  if (wk > 0) {
    #pragma unroll
    for (int r = 0; r < 4; ++r) red[wk-1][wc][4*lg + r][l15] = acc[r];
  }
  __syncthreads();
  if (wk == 0) {
    int c = 16*wc + l15;
    #pragma unroll
    for (int r = 0; r < 4; ++r) {
      int row = 4*lg + r;
      float a = acc[r] + red[0][wc][row][l15] + red[1][wc][row][l15] + red[2][wc][row][l15];
      int n = n_base + row;
      size_t idx = ((size_t)b*N_ + n)*32 + c;
      float v = 0.1f*h[idx] + 0.45f*zin[idx] + 0.45f*a;
      zout[idx] = v;
      zbTout[((size_t)b*32 + c)*N_ + n] = (unsigned short)f2bs(v);
    }
  }
}

// ---------------- K4-last: final iteration fused with out = relu(z) @ wo + bo ----------------
__global__ __launch_bounds__(512) void k_propm_bf_last(const unsigned short* __restrict__ adjbf,
    const unsigned short* __restrict__ zbT, const float* __restrict__ h,
    const float* __restrict__ zin, const float* __restrict__ wo,
    const float* __restrict__ bo, float* __restrict__ out)
{
  __shared__ float red[3][2][16][17];
  __shared__ float zfin[16][33];
  int b = blockIdx.x & 15;
  int g = blockIdx.x >> 4;
  int tid = threadIdx.x;
  int w = tid >> 6, l = tid & 63;
  int wk = w >> 1, wc = w & 1;
  int l15 = l & 15, lg = l >> 4;
  int n_base = g*16;

  const unsigned short* A = adjbf + ((size_t)b*N_ + n_base + l15)*N_ + wk*256;
  const unsigned short* Z = zbT + ((size_t)b*32 + 16*wc + l15)*N_ + wk*256;

  f32x4 acc0 = {0.f,0.f,0.f,0.f}, acc1 = {0.f,0.f,0.f,0.f};
  #pragma unroll
  for (int kc = 0; kc < 8; kc += 2) {
    int k0 = 32*kc + 8*lg;
    bf16x8 a0 = *reinterpret_cast<const bf16x8*>(A + k0);
    bf16x8 z0 = *reinterpret_cast<const bf16x8*>(Z + k0);
    bf16x8 a1 = *reinterpret_cast<const bf16x8*>(A + k0 + 32);
    bf16x8 z1 = *reinterpret_cast<const bf16x8*>(Z + k0 + 32);
    acc0 = MFMA16(a0, z0, acc0);
    acc1 = MFMA16(a1, z1, acc1);
  }
  f32x4 acc = acc0 + acc1;

  if (wk > 0) {
    #pragma unroll
    for (int r = 0; r < 4; ++r) red[wk-1][wc][4*lg + r][l15] = acc[r];
  }
  __syncthreads();
  if (wk == 0) {
    int c = 16*wc + l15;
    #pragma unroll
    for (int r = 0; r < 4; ++r) {
      int row = 4*lg + r;
      float a = acc[r] + red[0][wc][row][l15] + red[1][wc][row][l15] + red[2][wc][row][l15];
      int n = n_base + row;
      size_t idx = ((size_t)b*N_ + n)*32 + c;
      float v = 0.1f*h[idx] + 0.45f*zin[idx] + 0.45f*a;
      zfin[row][c] = fmaxf(v, 0.f);
    }
  }
  __syncthreads();
  if (tid < 192) {
    int n = tid / 12, o = tid - n*12;
    float acc2 = bo[o];
    #pragma unroll
    for (int cc = 0; cc < 32; ++cc) acc2 += zfin[n][cc] * wo[cc*O_ + o];
    out[((size_t)b*N_ + n_base + n)*O_ + o] = acc2;
  }
}

extern "C" void kernel_launch(void* const* d_in, const int* in_sizes, int n_in,
                              void* d_out, int out_size, void* d_ws, size_t ws_size,
                              hipStream_t stream)
{
  const float* x   = (const float*)d_in[0];
  const float* w1  = (const float*)d_in[1];
  const float* b1  = (const float*)d_in[2];
  const float* w2  = (const float*)d_in[3];
  const float* b2  = (const float*)d_in[4];
  const float* fw1 = (const float*)d_in[5];  const float* fb1 = (const float*)d_in[6];
  const float* gw1 = (const float*)d_in[7];  const float* gb1 = (const float*)d_in[8];
  const float* fw2 = (const float*)d_in[9];  const float* fb2 = (const float*)d_in[10];
  const float* gw2 = (const float*)d_in[11]; const float* gb2 = (const float*)d_in[12];
  const float* fw3 = (const float*)d_in[13]; const float* fb3 = (const float*)d_in[14];
  const float* gw3 = (const float*)d_in[15]; const float* gb3 = (const float*)d_in[16];
  const float* wo  = (const float*)d_in[17]; const float* bo  = (const float*)d_in[18];

  float* out = (float*)d_out;
  float* adj = out + (size_t)B_*N_*O_;

  char* ws = (char*)d_ws;
  unsigned short* Ubf  = (unsigned short*)ws;                       // 4 MB
  float* h             = (float*)(ws + (4ull<<20));                 // 2 MB
  float* z0            = (float*)(ws + (6ull<<20));                 // 2 MB
  float* z1            = (float*)(ws + (8ull<<20));                 // 2 MB
  unsigned short* zbT0 = (unsigned short*)(ws + (10ull<<20));       // 1 MB
  unsigned short* zbT1 = (unsigned short*)(ws + (11ull<<20));       // 1 MB
  unsigned short* adjbf= (unsigned short*)(ws + (12ull<<20));       // 32 MB

  k_u<<<B_*N_, 128, 0, stream>>>(x, w1, b1, w2, b2, Ubf);
  k_adj<<<B_*16, 512, 0, stream>>>(Ubf, adj, adjbf, 1);
  k_conv<<<B_*N_/16, 256, 0, stream>>>(x, fw1,fb1,gw1,gb1, fw2,fb2,gw2,gb2, fw3,fb3,gw3,gb3, h, zbT0);

  const float* zi = h;
  const unsigned short* zbi = zbT0;
  float* zfbuf[2] = {z0, z1};
  unsigned short* zbbuf[2] = {zbT1, zbT0};
  for (int it = 0; it < 9; ++it) {
    float* zo = zfbuf[it & 1];
    unsigned short* zbo = zbbuf[it & 1];
    k_propm_bf<<<B_*64, 512, 0, stream>>>(adjbf, zbi, h, zi, zo, zbo);
    zi = zo; zbi = zbo;
  }
  k_propm_bf_last<<<B_*64, 512, 0, stream>>>(adjbf, zbi, h, zi, wo, bo, out);
}